// Round 1
// baseline (167.112 us; speedup 1.0000x reference)
//
#include <hip/hip_runtime.h>

// Problem constants
#define BB   32
#define SS   100
#define TT   4
#define NCC2 500
#define NC3P 2001   // NUM_C3 + 1
#define DD   128

// Workspace layout (float offsets)
#define WS_U2   0        // u2[5][128]: a(v_c2), b(v_c3), c(v_d), d0(R0), d1(R1)
#define WS_U3   640      // u3[5][128]
#define WS_UC2V 1280     // upd_c2_val [B*S]
#define WS_UC3V 4480     // upd_c3_val [B*S*T]
#define WS_UC2I 17280    // upd_c2_idx [B*S]   (int, offset in ints from ws base)
#define WS_UC3I 20480    // upd_c3_idx [B*S*T] (int)

__device__ __forceinline__ float sigmoidf_(float x) { return 1.f / (1.f + expf(-x)); }

__device__ __forceinline__ float wred64(float v) {
#pragma unroll
    for (int m = 32; m; m >>= 1) v += __shfl_xor(v, m, 64);
    return v;
}

// ---------------------------------------------------------------------------
// K1: precompute u-vectors for MLP2 / MLP3 factorization.
// grid 2 (block 0 -> l2, block 1 -> l3), block 128.
__global__ void k_precompute_u(const float* __restrict__ l2W1,
                               const float* __restrict__ l3W1,
                               const float* __restrict__ v_c2,
                               const float* __restrict__ v_c3,
                               const float* __restrict__ v_d,
                               const float* __restrict__ Remb,
                               float* __restrict__ ws)
{
    const float* W = (blockIdx.x == 0) ? l2W1 : l3W1;
    float* U = ws + (blockIdx.x == 0 ? WS_U2 : WS_U3);
    int i = threadIdx.x;  // output channel
    float s0 = 0.f, s1 = 0.f, s2 = 0.f, s3 = 0.f, s4 = 0.f;
    for (int k = 0; k < DD; ++k) {
        float w0 = W[i * 512 + k];
        float w1 = W[i * 512 + 128 + k];
        float w2 = W[i * 512 + 256 + k];
        float w3 = W[i * 512 + 384 + k];
        s0 = fmaf(w0, v_c2[k], s0);
        s1 = fmaf(w1, v_c3[k], s1);
        s2 = fmaf(w2, v_d[k], s2);
        s3 = fmaf(w3, Remb[k], s3);
        s4 = fmaf(w3, Remb[128 + k], s4);
    }
    U[i] = s0; U[128 + i] = s1; U[256 + i] = s2; U[384 + i] = s3; U[512 + i] = s4;
}

// ---------------------------------------------------------------------------
// K2: fused GRU (blocks 0..31, one per batch) + C2/C3 scalar scan (blocks 32..63).
// The two roles are independent and run concurrently on disjoint CUs.
__global__ __launch_bounds__(384) void k_gru_scan(
    const int* __restrict__ c2_seq, const int* __restrict__ c3_seq,
    const int* __restrict__ d_seq,  const int* __restrict__ r_seq,
    const float* __restrict__ D_emb, const float* __restrict__ Remb,
    const float* __restrict__ v_d,
    const float* __restrict__ W_ih, const float* __restrict__ W_hh,
    const float* __restrict__ b_ih, const float* __restrict__ b_hh,
    const float* __restrict__ l2b1, const float* __restrict__ l2W2, const float* __restrict__ l2b2,
    const float* __restrict__ l3b1, const float* __restrict__ l3W2, const float* __restrict__ l3b2,
    float* __restrict__ ws, float* __restrict__ h_out)
{
    __shared__ __align__(16) float sh[NCC2 + NC3P];  // GRU uses first 512 floats

    int blk = blockIdx.x;
    if (blk < BB) {
        // ---------------- GRU role: b = blk ----------------
        const int b = blk;
        const int j = threadIdx.x;  // 0..383 = gate-channel row
        // W_hh row in registers
        float w[DD];
#pragma unroll
        for (int k = 0; k < DD; k += 4) {
            float4 t = *reinterpret_cast<const float4*>(&W_hh[j * DD + k]);
            w[k] = t.x; w[k + 1] = t.y; w[k + 2] = t.z; w[k + 3] = t.w;
        }
        // input-projection factors: gi = gamma*gd + g_r[r] + b_ih
        float gd = 0.f, gr0 = 0.f, gr1 = 0.f;
        for (int k = 0; k < DD; ++k) {
            gd  = fmaf(W_ih[j * 256 + k],       v_d[k],       gd);
            gr0 = fmaf(W_ih[j * 256 + 128 + k], Remb[k],      gr0);
            gr1 = fmaf(W_ih[j * 256 + 128 + k], Remb[128 + k], gr1);
        }
        const float bih = b_ih[j], bhh = b_hh[j];
        if (j < DD) sh[j] = 0.f;  // h0 = 0
        __syncthreads();

        for (int s = 0; s < SS; ++s) {
            const float gamma = D_emb[d_seq[b * SS + s]];
            const int   rr    = r_seq[b * SS + s];
            const float gi = fmaf(gamma, gd, (rr ? gr1 : gr0) + bih);
            float a0 = 0.f, a1 = 0.f, a2 = 0.f, a3 = 0.f;
#pragma unroll
            for (int k = 0; k < 32; ++k) {
                float4 hv = reinterpret_cast<const float4*>(sh)[k];
                a0 = fmaf(w[4 * k + 0], hv.x, a0);
                a1 = fmaf(w[4 * k + 1], hv.y, a1);
                a2 = fmaf(w[4 * k + 2], hv.z, a2);
                a3 = fmaf(w[4 * k + 3], hv.w, a3);
            }
            const float gh = ((a0 + a1) + (a2 + a3)) + bhh;
            if (j < DD) {
                sh[DD + j] = sigmoidf_(gi + gh);            // r gate
            } else if (j < 2 * DD) {
                sh[2 * DD + (j - DD)] = sigmoidf_(gi + gh); // z gate
            }
            __syncthreads();
            if (j >= 2 * DD) {
                int c = j - 2 * DD;
                sh[3 * DD + c] = tanhf(fmaf(sh[DD + c], gh, gi)); // n = tanh(gi + r*gh)
            }
            __syncthreads();
            if (j < DD) {
                float z = sh[2 * DD + j], n = sh[3 * DD + j], h = sh[j];
                float hn = (1.f - z) * n + z * h;
                sh[j] = hn;
                h_out[(size_t)(b * SS + s) * DD + j] = hn;
            }
            __syncthreads();
        }
    } else {
        // ---------------- scan role: b = blk - 32 ----------------
        const int b = blk - BB;
        const int l = threadIdx.x;
        const int ll = l & 63;  // all 6 waves compute redundantly; keeps barriers uniform
        float* C2s = sh;           // [500]
        float* C3s = sh + NCC2;    // [2001]
        for (int k = l; k < NCC2 + NC3P; k += 384) sh[k] = 0.f;

        const float* u2 = ws + WS_U2;
        const float* u3 = ws + WS_U3;
        const float u2a0 = u2[ll],       u2a1 = u2[64 + ll];
        const float u2b0 = u2[128 + ll], u2b1 = u2[192 + ll];
        const float u2c0 = u2[256 + ll], u2c1 = u2[320 + ll];
        const float u2d00 = u2[384 + ll], u2d01 = u2[448 + ll];
        const float u2d10 = u2[512 + ll], u2d11 = u2[576 + ll];
        const float u3a0 = u3[ll],       u3a1 = u3[64 + ll];
        const float u3b0 = u3[128 + ll], u3b1 = u3[192 + ll];
        const float u3c0 = u3[256 + ll], u3c1 = u3[320 + ll];
        const float u3d00 = u3[384 + ll], u3d01 = u3[448 + ll];
        const float u3d10 = u3[512 + ll], u3d11 = u3[576 + ll];
        const float b2_0 = l2b1[ll], b2_1 = l2b1[64 + ll];
        const float w2_0 = l2W2[ll], w2_1 = l2W2[64 + ll];
        const float b3_0 = l3b1[ll], b3_1 = l3b1[64 + ll];
        const float w3_0 = l3W2[ll], w3_1 = l3W2[64 + ll];
        const float c2bias = l2b2[0], c3bias = l3b2[0];

        float* uc2v = ws + WS_UC2V;
        float* uc3v = ws + WS_UC3V;
        int*   uc2i = reinterpret_cast<int*>(ws) + WS_UC2I;
        int*   uc3i = reinterpret_cast<int*>(ws) + WS_UC3I;
        __syncthreads();

        for (int s = 0; s < SS; ++s) {
            const int base = b * SS + s;
            const int c2i = c2_seq[base];
            const int4 c3v = reinterpret_cast<const int4*>(c3_seq)[base];
            const int i0 = c3v.x, i1 = c3v.y, i2 = c3v.z, i3 = c3v.w;
            const float gamma = D_emb[d_seq[base]];
            const int rr = r_seq[base];

            const float beta2 = C2s[c2i];
            const bool k0 = (i0 != 0), k1 = (i1 != 0), k2 = (i2 != 0), k3 = (i3 != 0);
            const float m0 = k0 ? 1.f : 0.f, m1 = k1 ? 1.f : 0.f, m2 = k2 ? 1.f : 0.f, m3 = k3 ? 1.f : 0.f;
            const float bt0 = C3s[i0], bt1 = C3s[i1], bt2 = C3s[i2], bt3 = C3s[i3];
            const float msum = m0 + m1 + m2 + m3;
            const float b3bar = (bt0 * m0 + bt1 * m1 + bt2 * m2 + bt3 * m3) / msum;

            const float ud20 = rr ? u2d10 : u2d00, ud21 = rr ? u2d11 : u2d01;
            const float ud30 = rr ? u3d10 : u3d00, ud31 = rr ? u3d11 : u3d01;

            // MLP2: new_c2
            float h20 = fmaf(beta2, u2a0, fmaf(b3bar, u2b0, fmaf(gamma, u2c0, ud20 + b2_0)));
            float h21 = fmaf(beta2, u2a1, fmaf(b3bar, u2b1, fmaf(gamma, u2c1, ud21 + b2_1)));
            float newc2 = wred64(fmaf(fmaxf(h20, 0.f), w2_0, fmaxf(h21, 0.f) * w2_1)) + c2bias;

            // MLP3 x4: new_c3[t]
            const float base30 = fmaf(beta2, u3a0, fmaf(gamma, u3c0, ud30 + b3_0));
            const float base31 = fmaf(beta2, u3a1, fmaf(gamma, u3c1, ud31 + b3_1));
            float ha, hb, q0, q1, q2, q3;
            ha = fmaf(bt0, u3b0, base30); hb = fmaf(bt0, u3b1, base31);
            q0 = wred64(fmaf(fmaxf(ha, 0.f), w3_0, fmaxf(hb, 0.f) * w3_1)) + c3bias;
            ha = fmaf(bt1, u3b0, base30); hb = fmaf(bt1, u3b1, base31);
            q1 = wred64(fmaf(fmaxf(ha, 0.f), w3_0, fmaxf(hb, 0.f) * w3_1)) + c3bias;
            ha = fmaf(bt2, u3b0, base30); hb = fmaf(bt2, u3b1, base31);
            q2 = wred64(fmaf(fmaxf(ha, 0.f), w3_0, fmaxf(hb, 0.f) * w3_1)) + c3bias;
            ha = fmaf(bt3, u3b0, base30); hb = fmaf(bt3, u3b1, base31);
            q3 = wred64(fmaf(fmaxf(ha, 0.f), w3_0, fmaxf(hb, 0.f) * w3_1)) + c3bias;

            // duplicate-aware final slot values (matches C3*(1-multi) + sum(new*oh))
            float val0 = 0.f, val1 = 0.f, val2 = 0.f, val3 = 0.f;
            {
                float c = m0 + ((k1 && i1 == i0) ? 1.f : 0.f) + ((k2 && i2 == i0) ? 1.f : 0.f) + ((k3 && i3 == i0) ? 1.f : 0.f);
                float qs = (k0 ? q0 : 0.f) + ((k1 && i1 == i0) ? q1 : 0.f) + ((k2 && i2 == i0) ? q2 : 0.f) + ((k3 && i3 == i0) ? q3 : 0.f);
                val0 = bt0 * (1.f - c) + qs;
            }
            {
                float c = ((k0 && i0 == i1) ? 1.f : 0.f) + m1 + ((k2 && i2 == i1) ? 1.f : 0.f) + ((k3 && i3 == i1) ? 1.f : 0.f);
                float qs = ((k0 && i0 == i1) ? q0 : 0.f) + (k1 ? q1 : 0.f) + ((k2 && i2 == i1) ? q2 : 0.f) + ((k3 && i3 == i1) ? q3 : 0.f);
                val1 = bt1 * (1.f - c) + qs;
            }
            {
                float c = ((k0 && i0 == i2) ? 1.f : 0.f) + ((k1 && i1 == i2) ? 1.f : 0.f) + m2 + ((k3 && i3 == i2) ? 1.f : 0.f);
                float qs = ((k0 && i0 == i2) ? q0 : 0.f) + ((k1 && i1 == i2) ? q1 : 0.f) + (k2 ? q2 : 0.f) + ((k3 && i3 == i2) ? q3 : 0.f);
                val2 = bt2 * (1.f - c) + qs;
            }
            {
                float c = ((k0 && i0 == i3) ? 1.f : 0.f) + ((k1 && i1 == i3) ? 1.f : 0.f) + ((k2 && i2 == i3) ? 1.f : 0.f) + m3;
                float qs = ((k0 && i0 == i3) ? q0 : 0.f) + ((k1 && i1 == i3) ? q1 : 0.f) + ((k2 && i2 == i3) ? q2 : 0.f) + (k3 ? q3 : 0.f);
                val3 = bt3 * (1.f - c) + qs;
            }

            if (l == 0) {
                C2s[c2i] = newc2;
                uc2i[base] = c2i;
                uc2v[base] = newc2;
                if (k0) C3s[i0] = val0;
                if (k1) C3s[i1] = val1;
                if (k2) C3s[i2] = val2;
                if (k3) C3s[i3] = val3;
                uc3i[base * 4 + 0] = k0 ? i0 : -1;  uc3v[base * 4 + 0] = val0;
                uc3i[base * 4 + 1] = k1 ? i1 : -1;  uc3v[base * 4 + 1] = val1;
                uc3i[base * 4 + 2] = k2 ? i2 : -1;  uc3v[base * 4 + 2] = val2;
                uc3i[base * 4 + 3] = k3 ? i3 : -1;  uc3v[base * 4 + 3] = val3;
            }
            __syncthreads();
        }
    }
}

// ---------------------------------------------------------------------------
// K3: alpha = MLP1(h_seq). grid B*S, block 64 (lane l handles channels l, l+64).
__global__ __launch_bounds__(64) void k_alpha(const float* __restrict__ h_seq,
                                              const float* __restrict__ W1,
                                              const float* __restrict__ b1,
                                              const float* __restrict__ W2,
                                              const float* __restrict__ b2,
                                              float* __restrict__ alpha)
{
    const int rs = blockIdx.x;
    const int l = threadIdx.x;
    const float* h = h_seq + (size_t)rs * DD;
    float a0 = b1[l], a1 = b1[64 + l];
    for (int k = 0; k < DD; k += 4) {
        float4 hv = *reinterpret_cast<const float4*>(&h[k]);
        float4 wa = *reinterpret_cast<const float4*>(&W1[l * DD + k]);
        float4 wb = *reinterpret_cast<const float4*>(&W1[(64 + l) * DD + k]);
        a0 = fmaf(wa.x, hv.x, fmaf(wa.y, hv.y, fmaf(wa.z, hv.z, fmaf(wa.w, hv.w, a0))));
        a1 = fmaf(wb.x, hv.x, fmaf(wb.y, hv.y, fmaf(wb.z, hv.z, fmaf(wb.w, hv.w, a1))));
    }
    float p = fmaf(fmaxf(a0, 0.f), W2[l], fmaxf(a1, 0.f) * W2[64 + l]);
    p = wred64(p);
    if (l == 0) alpha[rs] = p + b2[0];
}

// ---------------------------------------------------------------------------
// K4: reconstruct C2_seq/C3_seq snapshots. grid B*S, block 256.
// last-write-wins via packed (step+1)<<32 | float-bits, LDS atomicMax.
__global__ __launch_bounds__(256) void k_snapshot(const float* __restrict__ ws,
                                                  float* __restrict__ C2o,
                                                  float* __restrict__ C3o)
{
    __shared__ unsigned long long tab[NCC2 + NC3P];
    const int blk = blockIdx.x;
    const int b = blk / SS, s = blk % SS;
    const int tid = threadIdx.x;
    for (int k = tid; k < NCC2 + NC3P; k += 256) tab[k] = 0ull;
    __syncthreads();

    const float* uc2v = ws + WS_UC2V;
    const float* uc3v = ws + WS_UC3V;
    const int* uc2i = reinterpret_cast<const int*>(ws) + WS_UC2I;
    const int* uc3i = reinterpret_cast<const int*>(ws) + WS_UC3I;

    if (tid < SS && tid <= s) {
        int idx = uc2i[b * SS + tid];
        unsigned long long pv = (((unsigned long long)(tid + 1)) << 32) | (unsigned long long)__float_as_uint(uc2v[b * SS + tid]);
        atomicMax(&tab[idx], pv);
    }
    for (int e = tid; e < SS * TT; e += 256) {
        int st = e >> 2;
        if (st <= s) {
            int idx = uc3i[b * SS * TT + e];
            if (idx >= 0) {
                unsigned long long pv = (((unsigned long long)(st + 1)) << 32) | (unsigned long long)__float_as_uint(uc3v[b * SS * TT + e]);
                atomicMax(&tab[NCC2 + idx], pv);
            }
        }
    }
    __syncthreads();

    float* c2row = C2o + (size_t)(b * SS + s) * NCC2;
    float* c3row = C3o + (size_t)(b * SS + s) * NC3P;
    for (int k = tid; k < NCC2; k += 256) {
        unsigned long long e = tab[k];
        c2row[k] = e ? __uint_as_float((unsigned)e) : 0.f;
    }
    for (int k = tid; k < NC3P; k += 256) {
        unsigned long long e = tab[NCC2 + k];
        c3row[k] = e ? __uint_as_float((unsigned)e) : 0.f;
    }
}

// ---------------------------------------------------------------------------
extern "C" void kernel_launch(void* const* d_in, const int* in_sizes, int n_in,
                              void* d_out, int out_size, void* d_ws, size_t ws_size,
                              hipStream_t stream)
{
    (void)in_sizes; (void)n_in; (void)out_size; (void)ws_size;
    const int*   c2_seq = (const int*)d_in[0];
    const int*   c3_seq = (const int*)d_in[1];
    const int*   d_seq  = (const int*)d_in[2];
    const int*   r_seq  = (const int*)d_in[3];
    const float* D_emb  = (const float*)d_in[4];
    const float* Remb   = (const float*)d_in[5];
    const float* v_c2   = (const float*)d_in[6];
    const float* v_c3   = (const float*)d_in[7];
    const float* v_d    = (const float*)d_in[8];
    const float* W_ih   = (const float*)d_in[9];
    const float* W_hh   = (const float*)d_in[10];
    const float* b_ih   = (const float*)d_in[11];
    const float* b_hh   = (const float*)d_in[12];
    const float* l1W1   = (const float*)d_in[13];
    const float* l1b1   = (const float*)d_in[14];
    const float* l1W2   = (const float*)d_in[15];
    const float* l1b2   = (const float*)d_in[16];
    const float* l2W1   = (const float*)d_in[17];
    const float* l2b1   = (const float*)d_in[18];
    const float* l2W2   = (const float*)d_in[19];
    const float* l2b2   = (const float*)d_in[20];
    const float* l3W1   = (const float*)d_in[21];
    const float* l3b1   = (const float*)d_in[22];
    const float* l3W2   = (const float*)d_in[23];
    const float* l3b2   = (const float*)d_in[24];

    float* out   = (float*)d_out;
    float* alpha = out;                 // [B,S]            3200
    float* h_out = out + 3200;          // [B,S,128]        409600
    float* C2o   = out + 412800;        // [B,S,500]        1600000
    float* C3o   = out + 2012800;       // [B,S,2001]       6403200
    float* ws    = (float*)d_ws;

    k_precompute_u<<<2, 128, 0, stream>>>(l2W1, l3W1, v_c2, v_c3, v_d, Remb, ws);
    k_gru_scan<<<2 * BB, 384, 0, stream>>>(c2_seq, c3_seq, d_seq, r_seq, D_emb, Remb, v_d,
                                           W_ih, W_hh, b_ih, b_hh,
                                           l2b1, l2W2, l2b2, l3b1, l3W2, l3b2,
                                           ws, h_out);
    k_alpha<<<BB * SS, 64, 0, stream>>>(h_out, l1W1, l1b1, l1W2, l1b2, alpha);
    k_snapshot<<<BB * SS, 256, 0, stream>>>(ws, C2o, C3o);
}

// Round 2
// 152.056 us; speedup vs baseline: 1.0990x; 1.0990x over previous
//
#include <hip/hip_runtime.h>

#define BB   32
#define SS   100
#define TT   4
#define NCC2 500
#define NC3P 2001
#define DD   128

#define WS_U2 0
#define WS_U3 640

__device__ __forceinline__ float fast_rcp(float x) { return __builtin_amdgcn_rcpf(x); }
__device__ __forceinline__ float fast_sig(float x) { return fast_rcp(1.f + __expf(-x)); }
__device__ __forceinline__ float fast_tanh(float x) { return 1.f - 2.f * fast_rcp(__expf(2.f * x) + 1.f); }

// Full 64-lane sum via DPP; result valid in lane 63 only.
__device__ __forceinline__ float dpp_sum64(float x) {
    x += __int_as_float(__builtin_amdgcn_update_dpp(0, __float_as_int(x), 0x111, 0xf, 0xf, true)); // row_shr:1
    x += __int_as_float(__builtin_amdgcn_update_dpp(0, __float_as_int(x), 0x112, 0xf, 0xf, true)); // row_shr:2
    x += __int_as_float(__builtin_amdgcn_update_dpp(0, __float_as_int(x), 0x114, 0xf, 0xf, true)); // row_shr:4
    x += __int_as_float(__builtin_amdgcn_update_dpp(0, __float_as_int(x), 0x118, 0xf, 0xf, true)); // row_shr:8
    x += __int_as_float(__builtin_amdgcn_update_dpp(0, __float_as_int(x), 0x142, 0xa, 0xf, true)); // row_bcast:15
    x += __int_as_float(__builtin_amdgcn_update_dpp(0, __float_as_int(x), 0x143, 0xc, 0xf, true)); // row_bcast:31
    return x;
}

// ---------------------------------------------------------------------------
__global__ void k_precompute_u(const float* __restrict__ l2W1,
                               const float* __restrict__ l3W1,
                               const float* __restrict__ v_c2,
                               const float* __restrict__ v_c3,
                               const float* __restrict__ v_d,
                               const float* __restrict__ Remb,
                               float* __restrict__ ws)
{
    const float* W = (blockIdx.x == 0) ? l2W1 : l3W1;
    float* U = ws + (blockIdx.x == 0 ? WS_U2 : WS_U3);
    int i = threadIdx.x;
    float s0 = 0.f, s1 = 0.f, s2 = 0.f, s3 = 0.f, s4 = 0.f;
    for (int k = 0; k < DD; ++k) {
        float w0 = W[i * 512 + k];
        float w1 = W[i * 512 + 128 + k];
        float w2 = W[i * 512 + 256 + k];
        float w3 = W[i * 512 + 384 + k];
        s0 = fmaf(w0, v_c2[k], s0);
        s1 = fmaf(w1, v_c3[k], s1);
        s2 = fmaf(w2, v_d[k], s2);
        s3 = fmaf(w3, Remb[k], s3);
        s4 = fmaf(w3, Remb[128 + k], s4);
    }
    U[i] = s0; U[128 + i] = s1; U[256 + i] = s2; U[384 + i] = s3; U[512 + i] = s4;
}

// ---------------------------------------------------------------------------
// blocks 0..31: GRU (768 thr, k-split x2, W_hh register-resident, 2 barriers/step)
// blocks 32..63: scan (1 wave, barrier-free, DPP reductions, fused snapshot stores)
__global__ __launch_bounds__(768, 1) void k_main(
    const int* __restrict__ c2_seq, const int* __restrict__ c3_seq,
    const int* __restrict__ d_seq,  const int* __restrict__ r_seq,
    const float* __restrict__ D_emb, const float* __restrict__ Remb,
    const float* __restrict__ v_d,
    const float* __restrict__ W_ih, const float* __restrict__ W_hh,
    const float* __restrict__ b_ih, const float* __restrict__ b_hh,
    const float* __restrict__ l2b1, const float* __restrict__ l2W2, const float* __restrict__ l2b2,
    const float* __restrict__ l3b1, const float* __restrict__ l3W2, const float* __restrict__ l3b2,
    const float* __restrict__ ws, float* __restrict__ h_out,
    float* __restrict__ C2o, float* __restrict__ C3o)
{
    // union (floats): GRU: h[0..127] part[128..895] gpd[896] gr0p[1664] gr1p[2432] gam[3200] rr[3300]
    //                 scan: C2s[0..499] C3s[500..2500] tc2[2501] tc3[2601] tgam[3001] trr[3101]
    __shared__ __align__(16) float sh[3456];
    int* shi = (int*)sh;
    const int blk = blockIdx.x;
    const int t = threadIdx.x;

    if (blk < BB) {
        const int b = blk;
        const int p = (t >= 384) ? 1 : 0;
        const int j = t - p * 384;
        float4 wv[16];
        const float4* wrow = reinterpret_cast<const float4*>(W_hh + j * DD + p * 64);
#pragma unroll
        for (int i = 0; i < 16; ++i) wv[i] = wrow[i];

        float pd = 0.f, pr0 = 0.f, pr1 = 0.f;
        const float* wih_d = W_ih + j * 256 + p * 64;
        const float* wih_r = W_ih + j * 256 + 128 + p * 64;
#pragma unroll 4
        for (int k = 0; k < 64; ++k) {
            pd  = fmaf(wih_d[k], v_d[p * 64 + k],        pd);
            pr0 = fmaf(wih_r[k], Remb[p * 64 + k],       pr0);
            pr1 = fmaf(wih_r[k], Remb[128 + p * 64 + k], pr1);
        }
        sh[896 + t] = pd; sh[1664 + t] = pr0; sh[2432 + t] = pr1;
        if (t < DD) sh[t] = 0.f;
        if (t < SS) {
            sh[3200 + t]  = D_emb[d_seq[b * SS + t]];
            shi[3300 + t] = r_seq[b * SS + t];
        }
        __syncthreads();

        float gd_r=0,gd_z=0,gd_n=0, g0_r=0,g0_z=0,g0_n=0, g1_r=0,g1_z=0,g1_n=0;
        float bi_r=0,bi_z=0,bi_n=0, bh_r=0,bh_z=0,bh_n=0, h = 0.f;
        if (t < DD) {
            gd_r = sh[896+t]      + sh[896+t+384];
            gd_z = sh[896+t+128]  + sh[896+t+512];
            gd_n = sh[896+t+256]  + sh[896+t+640];
            g0_r = sh[1664+t]     + sh[1664+t+384];
            g0_z = sh[1664+t+128] + sh[1664+t+512];
            g0_n = sh[1664+t+256] + sh[1664+t+640];
            g1_r = sh[2432+t]     + sh[2432+t+384];
            g1_z = sh[2432+t+128] + sh[2432+t+512];
            g1_n = sh[2432+t+256] + sh[2432+t+640];
            bi_r = b_ih[t]; bi_z = b_ih[t+128]; bi_n = b_ih[t+256];
            bh_r = b_hh[t]; bh_z = b_hh[t+128]; bh_n = b_hh[t+256];
        }

        for (int s = 0; s < SS; ++s) {
            float a0=0.f,a1=0.f,a2=0.f,a3=0.f;
            const float4* hv4 = reinterpret_cast<const float4*>(sh) + p * 16;
#pragma unroll
            for (int i = 0; i < 16; ++i) {
                float4 hv = hv4[i];
                a0 = fmaf(wv[i].x, hv.x, a0);
                a1 = fmaf(wv[i].y, hv.y, a1);
                a2 = fmaf(wv[i].z, hv.z, a2);
                a3 = fmaf(wv[i].w, hv.w, a3);
            }
            sh[128 + t] = (a0 + a1) + (a2 + a3);
            __syncthreads();
            if (t < DD) {
                float ghr = sh[128+t]     + sh[128+t+384] + bh_r;
                float ghz = sh[128+t+128] + sh[128+t+512] + bh_z;
                float ghn = sh[128+t+256] + sh[128+t+640] + bh_n;
                float gamma = sh[3200 + s]; int rr = shi[3300 + s];
                float gir = fmaf(gamma, gd_r, (rr ? g1_r : g0_r) + bi_r);
                float giz = fmaf(gamma, gd_z, (rr ? g1_z : g0_z) + bi_z);
                float gin = fmaf(gamma, gd_n, (rr ? g1_n : g0_n) + bi_n);
                float r = fast_sig(gir + ghr);
                float z = fast_sig(giz + ghz);
                float n = fast_tanh(fmaf(r, ghn, gin));
                h = (1.f - z) * n + z * h;
                sh[t] = h;
                h_out[(size_t)(b * SS + s) * DD + t] = h;
            }
            __syncthreads();
        }
    } else if (t < 64) {
        const int b = blk - BB;
        float* C2s = sh;
        float* C3s = sh + NCC2;
        for (int k = t; k < NCC2 + NC3P; k += 64) sh[k] = 0.f;
        for (int k = t; k < SS; k += 64) {
            shi[2501 + k] = c2_seq[b * SS + k];
            sh[3001 + k]  = D_emb[d_seq[b * SS + k]];
            shi[3101 + k] = r_seq[b * SS + k];
        }
        for (int k = t; k < SS * TT; k += 64) shi[2601 + k] = c3_seq[b * SS * TT + k];

        const float* u2 = ws + WS_U2;
        const float* u3 = ws + WS_U3;
        const float u2a0 = u2[t],        u2a1 = u2[64 + t];
        const float u2b0 = u2[128 + t],  u2b1 = u2[192 + t];
        const float u2c0 = u2[256 + t],  u2c1 = u2[320 + t];
        const float u2d00 = u2[384 + t], u2d01 = u2[448 + t];
        const float u2d10 = u2[512 + t], u2d11 = u2[576 + t];
        const float u3a0 = u3[t],        u3a1 = u3[64 + t];
        const float u3b0 = u3[128 + t],  u3b1 = u3[192 + t];
        const float u3c0 = u3[256 + t],  u3c1 = u3[320 + t];
        const float u3d00 = u3[384 + t], u3d01 = u3[448 + t];
        const float u3d10 = u3[512 + t], u3d11 = u3[576 + t];
        const float b2_0 = l2b1[t], b2_1 = l2b1[64 + t];
        const float w2_0 = l2W2[t], w2_1 = l2W2[64 + t];
        const float b3_0 = l3b1[t], b3_1 = l3b1[64 + t];
        const float w3_0 = l3W2[t], w3_1 = l3W2[64 + t];
        const float c2bias = l2b2[0], c3bias = l3b2[0];

        for (int s = 0; s < SS; ++s) {
            const int rs = b * SS + s;
            const int c2i = shi[2501 + s];
            const int i0 = shi[2601 + 4*s + 0], i1 = shi[2601 + 4*s + 1];
            const int i2 = shi[2601 + 4*s + 2], i3 = shi[2601 + 4*s + 3];
            const float gamma = sh[3001 + s];
            const int rr = shi[3101 + s];

            const float beta2 = C2s[c2i];
            const bool k0 = (i0 != 0), k1 = (i1 != 0), k2 = (i2 != 0), k3 = (i3 != 0);
            const float m0 = k0 ? 1.f : 0.f, m1 = k1 ? 1.f : 0.f;
            const float m2 = k2 ? 1.f : 0.f, m3 = k3 ? 1.f : 0.f;
            const float bt0 = C3s[i0], bt1 = C3s[i1], bt2 = C3s[i2], bt3 = C3s[i3];
            const float msum = m0 + m1 + m2 + m3;
            const float b3bar = (bt0 * m0 + bt1 * m1 + bt2 * m2 + bt3 * m3) * fast_rcp(msum);

            const float ud20 = rr ? u2d10 : u2d00, ud21 = rr ? u2d11 : u2d01;
            const float ud30 = rr ? u3d10 : u3d00, ud31 = rr ? u3d11 : u3d01;

            float h20 = fmaf(beta2, u2a0, fmaf(b3bar, u2b0, fmaf(gamma, u2c0, ud20 + b2_0)));
            float h21 = fmaf(beta2, u2a1, fmaf(b3bar, u2b1, fmaf(gamma, u2c1, ud21 + b2_1)));
            float newc2 = dpp_sum64(fmaf(fmaxf(h20, 0.f), w2_0, fmaxf(h21, 0.f) * w2_1)) + c2bias;

            const float base30 = fmaf(beta2, u3a0, fmaf(gamma, u3c0, ud30 + b3_0));
            const float base31 = fmaf(beta2, u3a1, fmaf(gamma, u3c1, ud31 + b3_1));
            float ha, hb, q0, q1, q2, q3;
            ha = fmaf(bt0, u3b0, base30); hb = fmaf(bt0, u3b1, base31);
            q0 = dpp_sum64(fmaf(fmaxf(ha, 0.f), w3_0, fmaxf(hb, 0.f) * w3_1)) + c3bias;
            ha = fmaf(bt1, u3b0, base30); hb = fmaf(bt1, u3b1, base31);
            q1 = dpp_sum64(fmaf(fmaxf(ha, 0.f), w3_0, fmaxf(hb, 0.f) * w3_1)) + c3bias;
            ha = fmaf(bt2, u3b0, base30); hb = fmaf(bt2, u3b1, base31);
            q2 = dpp_sum64(fmaf(fmaxf(ha, 0.f), w3_0, fmaxf(hb, 0.f) * w3_1)) + c3bias;
            ha = fmaf(bt3, u3b0, base30); hb = fmaf(bt3, u3b1, base31);
            q3 = dpp_sum64(fmaf(fmaxf(ha, 0.f), w3_0, fmaxf(hb, 0.f) * w3_1)) + c3bias;

            float val0, val1, val2, val3;
            {
                float c = m0 + ((k1 && i1 == i0) ? 1.f : 0.f) + ((k2 && i2 == i0) ? 1.f : 0.f) + ((k3 && i3 == i0) ? 1.f : 0.f);
                float qs = (k0 ? q0 : 0.f) + ((k1 && i1 == i0) ? q1 : 0.f) + ((k2 && i2 == i0) ? q2 : 0.f) + ((k3 && i3 == i0) ? q3 : 0.f);
                val0 = bt0 * (1.f - c) + qs;
            }
            {
                float c = ((k0 && i0 == i1) ? 1.f : 0.f) + m1 + ((k2 && i2 == i1) ? 1.f : 0.f) + ((k3 && i3 == i1) ? 1.f : 0.f);
                float qs = ((k0 && i0 == i1) ? q0 : 0.f) + (k1 ? q1 : 0.f) + ((k2 && i2 == i1) ? q2 : 0.f) + ((k3 && i3 == i1) ? q3 : 0.f);
                val1 = bt1 * (1.f - c) + qs;
            }
            {
                float c = ((k0 && i0 == i2) ? 1.f : 0.f) + ((k1 && i1 == i2) ? 1.f : 0.f) + m2 + ((k3 && i3 == i2) ? 1.f : 0.f);
                float qs = ((k0 && i0 == i2) ? q0 : 0.f) + ((k1 && i1 == i2) ? q1 : 0.f) + (k2 ? q2 : 0.f) + ((k3 && i3 == i2) ? q3 : 0.f);
                val2 = bt2 * (1.f - c) + qs;
            }
            {
                float c = ((k0 && i0 == i3) ? 1.f : 0.f) + ((k1 && i1 == i3) ? 1.f : 0.f) + ((k2 && i2 == i3) ? 1.f : 0.f) + m3;
                float qs = ((k0 && i0 == i3) ? q0 : 0.f) + ((k1 && i1 == i3) ? q1 : 0.f) + ((k2 && i2 == i3) ? q2 : 0.f) + (k3 ? q3 : 0.f);
                val3 = bt3 * (1.f - c) + qs;
            }

            if (t == 63) {
                C2s[c2i] = newc2;
                if (k0) C3s[i0] = val0;
                if (k1) C3s[i1] = val1;
                if (k2) C3s[i2] = val2;
                if (k3) C3s[i3] = val3;
            }

            // fused snapshot store of row (b,s); same-wave DS ordering makes
            // lane63's writes visible to the reads below.
            float* c2row = C2o + (size_t)rs * NCC2;
            float* c3row = C3o + (size_t)rs * NC3P;
            *reinterpret_cast<float4*>(c2row + 4 * t) = *reinterpret_cast<const float4*>(C2s + 4 * t);
            if (t < 61)
                *reinterpret_cast<float4*>(c2row + 256 + 4 * t) = *reinterpret_cast<const float4*>(C2s + 256 + 4 * t);
            const int p0 = (4 - (rs & 3)) & 3;
            const int tail = (2001 - p0) & 3;
            const int dt = 2001 - tail;
            if (t < p0) c3row[t] = C3s[t];
            if (t < tail) c3row[dt + t] = C3s[dt + t];
#pragma unroll
            for (int i = 0; i < 8; ++i) {
                int d = p0 + 4 * (i * 64 + t);
                if (d + 3 <= 2000) {
                    float4 v;
                    v.x = C3s[d]; v.y = C3s[d + 1]; v.z = C3s[d + 2]; v.w = C3s[d + 3];
                    *reinterpret_cast<float4*>(c3row + d) = v;
                }
            }
        }
    }
}

// ---------------------------------------------------------------------------
// alpha: block 512 = 8 waves, one (b,s) row per wave; W1 stream shared via L1.
__global__ __launch_bounds__(512) void k_alpha(const float* __restrict__ h_seq,
                                               const float* __restrict__ W1,
                                               const float* __restrict__ b1,
                                               const float* __restrict__ W2,
                                               const float* __restrict__ b2,
                                               float* __restrict__ alpha)
{
    const int w = threadIdx.x >> 6, l = threadIdx.x & 63;
    const int rs = blockIdx.x * 8 + w;
    const float* h = h_seq + (size_t)rs * DD;
    float a0 = b1[l], a1 = b1[64 + l];
    for (int k = 0; k < DD; k += 4) {
        float4 hv = *reinterpret_cast<const float4*>(&h[k]);
        float4 wa = *reinterpret_cast<const float4*>(&W1[l * DD + k]);
        float4 wb = *reinterpret_cast<const float4*>(&W1[(64 + l) * DD + k]);
        a0 = fmaf(wa.x, hv.x, fmaf(wa.y, hv.y, fmaf(wa.z, hv.z, fmaf(wa.w, hv.w, a0))));
        a1 = fmaf(wb.x, hv.x, fmaf(wb.y, hv.y, fmaf(wb.z, hv.z, fmaf(wb.w, hv.w, a1))));
    }
    float pp = fmaf(fmaxf(a0, 0.f), W2[l], fmaxf(a1, 0.f) * W2[64 + l]);
    pp = dpp_sum64(pp);
    if (l == 63) alpha[rs] = pp + b2[0];
}

// ---------------------------------------------------------------------------
extern "C" void kernel_launch(void* const* d_in, const int* in_sizes, int n_in,
                              void* d_out, int out_size, void* d_ws, size_t ws_size,
                              hipStream_t stream)
{
    (void)in_sizes; (void)n_in; (void)out_size; (void)ws_size;
    const int*   c2_seq = (const int*)d_in[0];
    const int*   c3_seq = (const int*)d_in[1];
    const int*   d_seq  = (const int*)d_in[2];
    const int*   r_seq  = (const int*)d_in[3];
    const float* D_emb  = (const float*)d_in[4];
    const float* Remb   = (const float*)d_in[5];
    const float* v_c2   = (const float*)d_in[6];
    const float* v_c3   = (const float*)d_in[7];
    const float* v_d    = (const float*)d_in[8];
    const float* W_ih   = (const float*)d_in[9];
    const float* W_hh   = (const float*)d_in[10];
    const float* b_ih   = (const float*)d_in[11];
    const float* b_hh   = (const float*)d_in[12];
    const float* l1W1   = (const float*)d_in[13];
    const float* l1b1   = (const float*)d_in[14];
    const float* l1W2   = (const float*)d_in[15];
    const float* l1b2   = (const float*)d_in[16];
    const float* l2W1   = (const float*)d_in[17];
    const float* l2b1   = (const float*)d_in[18];
    const float* l2W2   = (const float*)d_in[19];
    const float* l2b2   = (const float*)d_in[20];
    const float* l3W1   = (const float*)d_in[21];
    const float* l3b1   = (const float*)d_in[22];
    const float* l3W2   = (const float*)d_in[23];
    const float* l3b2   = (const float*)d_in[24];

    float* out   = (float*)d_out;
    float* alpha = out;                 // [B,S]
    float* h_out = out + 3200;          // [B,S,128]
    float* C2o   = out + 412800;        // [B,S,500]
    float* C3o   = out + 2012800;       // [B,S,2001]
    float* ws    = (float*)d_ws;

    k_precompute_u<<<2, 128, 0, stream>>>(l2W1, l3W1, v_c2, v_c3, v_d, Remb, ws);
    k_main<<<2 * BB, 768, 0, stream>>>(c2_seq, c3_seq, d_seq, r_seq, D_emb, Remb, v_d,
                                       W_ih, W_hh, b_ih, b_hh,
                                       l2b1, l2W2, l2b2, l3b1, l3W2, l3b2,
                                       ws, h_out, C2o, C3o);
    k_alpha<<<400, 512, 0, stream>>>(h_out, l1W1, l1b1, l1W2, l1b2, alpha);
}